// Round 17
// baseline (308.612 us; speedup 1.0000x reference)
//
#include <hip/hip_runtime.h>
#include <hip/hip_bf16.h>

#define B_ 2
#define L_ 256
#define T_ 250
#define D_ 1024
#define NH_ 16
#define DH_ 64
#define CRv_ 16
#define HID_ 64
#define CL_ 16
#define OUT_ 1024
#define MEMROWS_ 64001L

typedef __attribute__((ext_vector_type(2))) _Float16 h16x2;
typedef __attribute__((ext_vector_type(8))) _Float16 h16x8;
typedef __attribute__((ext_vector_type(4))) float f32x4;
typedef __attribute__((ext_vector_type(16))) float f32x16;

__device__ __forceinline__ h16x2 cvt_pk(float lo, float hi) {
    return __builtin_bit_cast(h16x2, __builtin_amdgcn_cvt_pkrtz(lo, hi));
}
__device__ __forceinline__ unsigned cvt_pku(float lo, float hi) {
    return __builtin_bit_cast(unsigned, __builtin_amdgcn_cvt_pkrtz(lo, hi));
}

struct H4 { h16x2 a, b, c, d; };
__device__ __forceinline__ h16x8 packH4(h16x2 a, h16x2 b, h16x2 c, h16x2 d) {
    H4 h{a, b, c, d};
    return __builtin_bit_cast(h16x8, h);
}
struct U4 { unsigned a, b, c, d; };
__device__ __forceinline__ h16x8 packU4(unsigned a, unsigned b, unsigned c, unsigned d) {
    U4 u{a, b, c, d};
    return __builtin_bit_cast(h16x8, u);
}

// ---- guaranteed-VOP3P packed f16 ops ----
__device__ __forceinline__ unsigned pk_fma(unsigned a, unsigned b, unsigned c) {
    unsigned d; asm("v_pk_fma_f16 %0, %1, %2, %3" : "=v"(d) : "v"(a), "v"(b), "v"(c)); return d;
}
__device__ __forceinline__ unsigned pk_mul(unsigned a, unsigned b) {
    unsigned d; asm("v_pk_mul_f16 %0, %1, %2" : "=v"(d) : "v"(a), "v"(b)); return d;
}
__device__ __forceinline__ unsigned pk_add(unsigned a, unsigned b) {
    unsigned d; asm("v_pk_add_f16 %0, %1, %2" : "=v"(d) : "v"(a), "v"(b)); return d;
}
__device__ __forceinline__ unsigned pk_max(unsigned a, unsigned b) {
    unsigned d; asm("v_pk_max_f16 %0, %1, %2" : "=v"(d) : "v"(a), "v"(b)); return d;
}
__device__ __forceinline__ unsigned pk_min(unsigned a, unsigned b) {
    unsigned d; asm("v_pk_min_f16 %0, %1, %2" : "=v"(d) : "v"(a), "v"(b)); return d;
}

struct GC { unsigned c0, c1, c2, c3, c4, clo, chi; };
__device__ __forceinline__ GC make_gc() {
    GC g;
    g.c0  = cvt_pku( 1.5957600f,   1.5957600f);
    g.c1  = cvt_pku(-1.0445624f,  -1.0445624f);
    g.c2  = cvt_pku( 0.5417632f,   0.5417632f);
    g.c3  = cvt_pku(-0.15817472f, -0.15817472f);
    g.c4  = cvt_pku( 0.018604288f, 0.018604288f);
    g.clo = cvt_pku(-1.75f, -1.75f);
    g.chi = cvt_pku( 1.75f,  1.75f);
    return g;
}

// Packed-f16 gelu * w2 accumulate, PRE-HALVED input aH = x/2. 10 VOP3P / 2 values.
__device__ __forceinline__ void gelu_w2_asm(unsigned aH, unsigned w, unsigned& pacc, const GC& gc) {
    unsigned t = pk_min(pk_max(aH, gc.clo), gc.chi);
    unsigned s = pk_mul(t, t);
    unsigned p = pk_fma(gc.c4, s, gc.c3);
    p = pk_fma(p, s, gc.c2);
    p = pk_fma(p, s, gc.c1);
    p = pk_fma(p, s, gc.c0);
    unsigned e = pk_mul(t, p);
    unsigned g = pk_fma(aH, e, aH);
    pacc = pk_fma(g, w, pacc);
}

#define WAITV(n)  asm volatile("s_waitcnt vmcnt(" #n ")" ::: "memory")
#define WAITLG()  asm volatile("s_waitcnt lgkmcnt(0)" ::: "memory")
#define MEMBAR()  asm volatile("" ::: "memory")

// ---- Stage 1: R15 structure (8 waves share 16x512 LDS tile, dbuf, 32x32x16 MFMA),
// but staging via REG path (global_load_dwordx4 -> VGPR -> ds_write_b128)
// instead of global_load_lds DMA. A/B test of the DMA bandwidth ceiling.
__global__ __launch_bounds__(512, 4) void k_stage1(
    const float* __restrict__ mem, const float* __restrict__ dim_pe,
    const float* __restrict__ W1, const float* __restrict__ b1,
    const float* __restrict__ W2, const float* __restrict__ b2,
    _Float16* __restrict__ vbuf)
{
    extern __shared__ float stage[];            // [2][16][512] = 64 KB

    const int blk   = blockIdx.x;               // ((b*16+cl)*8 + tch)*2 + dhalf
    const int dhalf = blk & 1;
    const int tch   = (blk >> 1) & 7;
    const int cl    = (blk >> 4) & 15;
    const int b     = blk >> 8;
    const int lane  = threadIdx.x & 63;
    const int wv    = threadIdx.x >> 6;         // 0..7
    const int nh    = dhalf * 8 + wv;
    const int h     = lane >> 5;                // k-half (cr 8h..8h+7)
    const int l31   = lane & 31;

    const float* membase = mem + (long)b * MEMROWS_ * D_;
    _Float16* vrow = vbuf + (long)(b * CL_ + cl) * T_ * D_;
    const int t0   = tch * 31 + (tch < 2 ? tch : 2);
    const int tend = (tch < 2) ? 32 : 31;

    const GC gc = make_gc();

    // A-fragments (W1^T, pre-halved): lane: f = fh*32 + l31, k = 8h + j
    h16x8 afrag[2];
#pragma unroll
    for (int fh = 0; fh < 2; ++fh) {
        h16x2 q[4];
#pragma unroll
        for (int jp = 0; jp < 4; ++jp) {
            float w0 = 0.5f * W1[(nh * CRv_ + 8 * h + 2 * jp + 0) * HID_ + fh * 32 + l31];
            float w1 = 0.5f * W1[(nh * CRv_ + 8 * h + 2 * jp + 1) * HID_ + fh * 32 + l31];
            q[jp] = cvt_pk(w0, w1);
        }
        afrag[fh] = packH4(q[0], q[1], q[2], q[3]);
    }

    // C-input: b1/2, rows per 32x32 C layout
    f32x16 ci[2];
#pragma unroll
    for (int fh = 0; fh < 2; ++fh)
#pragma unroll
        for (int rr = 0; rr < 16; ++rr)
            ci[fh][rr] = 0.5f * b1[nh * HID_ + fh * 32 + (rr & 3) + 8 * (rr >> 2) + 4 * h];

    // W2 pk pairs matching acc reg pairs
    unsigned w2u[2][8];
#pragma unroll
    for (int fh = 0; fh < 2; ++fh)
#pragma unroll
        for (int m = 0; m < 8; ++m) {
            const int flo = ((2 * m) & 3) + 8 * (m >> 1) + 4 * h + fh * 32;
            w2u[fh][m] = cvt_pku(W2[nh * HID_ + flo], W2[nh * HID_ + flo + 1]);
        }

    // pe addend for B-frags
    unsigned peq[2][4];
#pragma unroll
    for (int dh = 0; dh < 2; ++dh) {
        const int d0 = nh * DH_ + dh * 32 + l31;
#pragma unroll
        for (int m = 0; m < 4; ++m)
            peq[dh][m] = cvt_pku(dim_pe[(8 * h + 2 * m + 0) * D_ + d0],
                                 dim_pe[(8 * h + 2 * m + 1) * D_ + d0]);
    }
    const float b2s = b2[nh];

    // Staging: wave wv owns rows 2wv, 2wv+1; four 1KB loads per tile (reg path).
    const int r0 = 2 * wv, r1 = 2 * wv + 1;
    const float* gp0 = membase + ((size_t)(cl * CRv_ + r0) * T_ + t0) * D_ + dhalf * 512 +   0 + lane * 4;
    const float* gp1 = membase + ((size_t)(cl * CRv_ + r0) * T_ + t0) * D_ + dhalf * 512 + 256 + lane * 4;
    const float* gp2 = membase + ((size_t)(cl * CRv_ + r1) * T_ + t0) * D_ + dhalf * 512 +   0 + lane * 4;
    const float* gp3 = membase + ((size_t)(cl * CRv_ + r1) * T_ + t0) * D_ + dhalf * 512 + 256 + lane * 4;

    // LDS write targets (per-lane)
    float* const wp0 = stage + r0 * 512 +   0 + lane * 4;
    float* const wp1 = stage + r0 * 512 + 256 + lane * 4;
    float* const wp2 = stage + r1 * 512 +   0 + lane * 4;
    float* const wp3 = stage + r1 * 512 + 256 + lane * 4;

    uint4 rg0, rg1, rg2, rg3;

#define LOADR() do { \
    rg0 = *reinterpret_cast<const uint4*>(gp0); \
    rg1 = *reinterpret_cast<const uint4*>(gp1); \
    rg2 = *reinterpret_cast<const uint4*>(gp2); \
    rg3 = *reinterpret_cast<const uint4*>(gp3); \
    gp0 += D_; gp1 += D_; gp2 += D_; gp3 += D_; } while (0)

#define WRITES(bf) do { \
    const int off = (bf) * 8192; \
    *reinterpret_cast<uint4*>(wp0 + off) = rg0; \
    *reinterpret_cast<uint4*>(wp1 + off) = rg1; \
    *reinterpret_cast<uint4*>(wp2 + off) = rg2; \
    *reinterpret_cast<uint4*>(wp3 + off) = rg3; } while (0)

    // prologue: t0 -> regs -> buf0; t1 loads in flight; barrier
    LOADR();
    WAITV(0);
    WRITES(0);
    LOADR();                       // t1 -> regs (in flight across compute of t0)
    WAITLG();
    __builtin_amdgcn_s_barrier();
    MEMBAR();

#pragma unroll 1
    for (int tt = 0; tt < tend; ++tt) {
        const float* bufp = stage + (tt & 1) * 8192;

        // B-fragments: lane: d_local = l31, k = 8h + j; x + pe in f16
        h16x8 bfr[2];
#pragma unroll
        for (int dh = 0; dh < 2; ++dh) {
            const int col = wv * 64 + dh * 32 + l31;
            float x0 = bufp[(8 * h + 0) * 512 + col];
            float x1 = bufp[(8 * h + 1) * 512 + col];
            float x2 = bufp[(8 * h + 2) * 512 + col];
            float x3 = bufp[(8 * h + 3) * 512 + col];
            float x4 = bufp[(8 * h + 4) * 512 + col];
            float x5 = bufp[(8 * h + 5) * 512 + col];
            float x6 = bufp[(8 * h + 6) * 512 + col];
            float x7 = bufp[(8 * h + 7) * 512 + col];
            unsigned u0 = pk_add(cvt_pku(x0, x1), peq[dh][0]);
            unsigned u1 = pk_add(cvt_pku(x2, x3), peq[dh][1]);
            unsigned u2 = pk_add(cvt_pku(x4, x5), peq[dh][2]);
            unsigned u3 = pk_add(cvt_pku(x6, x7), peq[dh][3]);
            bfr[dh] = packU4(u0, u1, u2, u3);
        }

        unsigned p00 = 0u, p01 = 0u, p10 = 0u, p11 = 0u;
        {
            f32x16 a00 = __builtin_amdgcn_mfma_f32_32x32x16_f16(afrag[0], bfr[0], ci[0], 0, 0, 0);
            f32x16 a01 = __builtin_amdgcn_mfma_f32_32x32x16_f16(afrag[0], bfr[1], ci[0], 0, 0, 0);
#pragma unroll
            for (int m = 0; m < 8; ++m) {
                unsigned am0 = cvt_pku(a00[2 * m], a00[2 * m + 1]);
                gelu_w2_asm(am0, w2u[0][m], p00, gc);
                unsigned am1 = cvt_pku(a01[2 * m], a01[2 * m + 1]);
                gelu_w2_asm(am1, w2u[0][m], p01, gc);
            }
        }
        {
            f32x16 a10 = __builtin_amdgcn_mfma_f32_32x32x16_f16(afrag[1], bfr[0], ci[1], 0, 0, 0);
            f32x16 a11 = __builtin_amdgcn_mfma_f32_32x32x16_f16(afrag[1], bfr[1], ci[1], 0, 0, 0);
#pragma unroll
            for (int m = 0; m < 8; ++m) {
                unsigned am0 = cvt_pku(a10[2 * m], a10[2 * m + 1]);
                gelu_w2_asm(am0, w2u[1][m], p10, gc);
                unsigned am1 = cvt_pku(a11[2 * m], a11[2 * m + 1]);
                gelu_w2_asm(am1, w2u[1][m], p11, gc);
            }
        }

        // Reduce: f-halves, cross-pk-half in f32, one shfl_xor(32)
        h16x2 pd0 = __builtin_bit_cast(h16x2, pk_add(p00, p10));
        h16x2 pd1 = __builtin_bit_cast(h16x2, pk_add(p01, p11));
        float o0 = (float)pd0[0] + (float)pd0[1];
        float o1 = (float)pd1[0] + (float)pd1[1];
        o0 += __shfl_xor(o0, 32);
        o1 += __shfl_xor(o1, 32);
        float ov = (h == 0) ? o0 : o1;

        // stage t+1 into the other buffer; issue t+2 loads; then store result
        if (tt + 1 < tend) {
            WAITV(0);                              // t+1 regs landed (prev store long retired)
            WRITES((tt + 1) & 1);
            if (tt + 2 < tend) LOADR();            // t+2 -> regs, in flight across next compute
        }
        vrow[(size_t)(t0 + tt) * D_ + nh * DH_ + lane] = (_Float16)(ov + b2s);
        MEMBAR();
        WAITLG();                                   // ds_writes visible
        __builtin_amdgcn_s_barrier();
        MEMBAR();
    }
#undef LOADR
#undef WRITES
}

// ---- Stage 2: h-MLP over t = tc*16+cr (pad rows -> nonsense); 16x16 path, f16 out.
__global__ __launch_bounds__(256) void k_stage2(
    const _Float16* __restrict__ vbuf, const float* __restrict__ mem,
    const float* __restrict__ W1, const float* __restrict__ b1,
    const float* __restrict__ W2, const float* __restrict__ b2,
    _Float16* __restrict__ hbuf)
{
    const int blk = blockIdx.x;                // ((b*CL + cl)*16 + tc)*4 + nhg
    const int nhg = blk & 3;
    const int tc  = (blk >> 2) & 15;
    const int cl  = (blk >> 6) & 15;
    const int b   = blk >> 10;
    const int lane = threadIdx.x & 63;
    const int wv   = threadIdx.x >> 6;
    const int nh   = nhg * 4 + wv;
    const int g    = lane >> 4;
    const int fl   = lane & 15;
    const int kbase = (8 * g) & 15;
    const bool klive = (g < 2);

    const _Float16* vrow = vbuf + (long)(b * CL_ + cl) * T_ * D_;
    const float* nons = mem + ((long)b * MEMROWS_ + (long)L_ * T_) * D_;

    const GC gc = make_gc();

    h16x8 bfragA[4];
    f32x4 ci[4];
    unsigned w2u[8];
#pragma unroll
    for (int cn = 0; cn < 4; ++cn) {
        h16x2 q[4];
#pragma unroll
        for (int jp = 0; jp < 4; ++jp) {
            float w0 = 0.5f * W1[(nh * CRv_ + kbase + 2 * jp + 0) * HID_ + cn * 16 + fl];
            float w1 = 0.5f * W1[(nh * CRv_ + kbase + 2 * jp + 1) * HID_ + cn * 16 + fl];
            h16x2 qq = cvt_pk(w0, w1);
            if (!klive) { qq[0] = (_Float16)0.f; qq[1] = (_Float16)0.f; }
            q[jp] = qq;
        }
        bfragA[cn] = packH4(q[0], q[1], q[2], q[3]);
#pragma unroll
        for (int r = 0; r < 4; ++r) ci[cn][r] = 0.5f * b1[nh * HID_ + cn * 16 + 4 * g + r];
        w2u[2 * cn + 0] = cvt_pku(W2[nh * HID_ + cn * 16 + 4 * g + 0],
                                  W2[nh * HID_ + cn * 16 + 4 * g + 1]);
        w2u[2 * cn + 1] = cvt_pku(W2[nh * HID_ + cn * 16 + 4 * g + 2],
                                  W2[nh * HID_ + cn * 16 + 4 * g + 3]);
    }
    const float b2s = b2[nh];

#pragma unroll 1
    for (int ct = 0; ct < 4; ++ct) {
        const int d0 = nh * DH_ + ct * 16 + fl;
        const _Float16 nv = (_Float16)nons[d0];

        h16x2 q[4];
#pragma unroll
        for (int jp = 0; jp < 4; ++jp) {
            h16x2 qq;
#pragma unroll
            for (int e = 0; e < 2; ++e) {
                const int t   = tc * CRv_ + kbase + 2 * jp + e;
                const int tcl = (t < T_) ? t : (T_ - 1);
                _Float16 us = vrow[tcl * D_ + d0];
                qq[e] = (t < T_) ? us : nv;
            }
            q[jp] = qq;
        }
        h16x8 af = packH4(q[0], q[1], q[2], q[3]);

        f32x4 acc[4];
#pragma unroll
        for (int cn = 0; cn < 4; ++cn)
            acc[cn] = __builtin_amdgcn_mfma_f32_16x16x32_f16(bfragA[cn], af, ci[cn], 0, 0, 0);

        unsigned pc0 = 0u, pc1 = 0u;
#pragma unroll
        for (int cn = 0; cn < 4; ++cn) {
            unsigned a01 = cvt_pku(acc[cn][0], acc[cn][1]);
            unsigned a23 = cvt_pku(acc[cn][2], acc[cn][3]);
            gelu_w2_asm(a01, w2u[2 * cn + 0], pc0, gc);
            gelu_w2_asm(a23, w2u[2 * cn + 1], pc1, gc);
        }
        h16x2 P = __builtin_bit_cast(h16x2, pk_add(pc0, pc1));
        float pr = (float)P[0] + (float)P[1];
        pr += __shfl_xor(pr, 16);
        pr += __shfl_xor(pr, 32);

        if (g == 0)
            hbuf[(long)((b * CL_ + cl) * 16 + tc) * D_ + d0] = (_Float16)(pr + b2s);
    }
}

// ---- Stage 3: C(512x1024) = H(f16) @ Wp^T + bias via f16 MFMA, f32 accum.
__global__ __launch_bounds__(256) void k_proj(
    const _Float16* __restrict__ H, const float* __restrict__ Wp,
    const float* __restrict__ bias, float* __restrict__ Cout)
{
    __shared__ _Float16 Ht[64][40];
    __shared__ _Float16 Wt[32][40];

    const int bn = blockIdx.x & 31;
    const int bm = blockIdx.x >> 5;
    const int tid = threadIdx.x;
    const int lane = tid & 63, wv = tid >> 6;
    const int g = lane >> 4, fl = lane & 15;
    const int m0 = bm * 64, n0 = bn * 32;

    const int hrow = tid >> 2, hko = (tid & 3) * 8;
    const int wrow = tid >> 3, wko = (tid & 7) * 4;

    const int nw  = (wv & 1) * 16;
    const int mwb = (wv >> 1) * 32;

    f32x4 acc[2] = {{0.f,0.f,0.f,0.f},{0.f,0.f,0.f,0.f}};

    for (int k0 = 0; k0 < 1024; k0 += 32) {
        uint4 hv = *reinterpret_cast<const uint4*>(&H[(size_t)(m0 + hrow) * OUT_ + k0 + hko]);
        *reinterpret_cast<uint4*>(&Ht[hrow][hko]) = hv;
        float4 wf = *reinterpret_cast<const float4*>(&Wp[(size_t)(n0 + wrow) * D_ + k0 + wko]);
        uint2 wu;
        wu.x = cvt_pku(wf.x, wf.y);
        wu.y = cvt_pku(wf.z, wf.w);
        *reinterpret_cast<uint2*>(&Wt[wrow][wko]) = wu;
        __syncthreads();

        h16x8 wfrag = *reinterpret_cast<const h16x8*>(&Wt[nw + fl][g * 8]);
        h16x8 hfrag0 = *reinterpret_cast<const h16x8*>(&Ht[mwb +  0 + fl][g * 8]);
        h16x8 hfrag1 = *reinterpret_cast<const h16x8*>(&Ht[mwb + 16 + fl][g * 8]);
        acc[0] = __builtin_amdgcn_mfma_f32_16x16x32_f16(hfrag0, wfrag, acc[0], 0, 0, 0);
        acc[1] = __builtin_amdgcn_mfma_f32_16x16x32_f16(hfrag1, wfrag, acc[1], 0, 0, 0);
        __syncthreads();
    }

    const int n = n0 + nw + fl;
    const float bv = bias[n];
#pragma unroll
    for (int mt = 0; mt < 2; ++mt) {
#pragma unroll
        for (int r = 0; r < 4; ++r) {
            const int m = m0 + mwb + mt * 16 + 4 * g + r;
            Cout[(size_t)m * OUT_ + n] = acc[mt][r] + bv;
        }
    }
}

extern "C" void kernel_launch(void* const* d_in, const int* in_sizes, int n_in,
                              void* d_out, int out_size, void* d_ws, size_t ws_size,
                              hipStream_t stream) {
    const float* mem    = (const float*)d_in[0];
    const float* dim_pe = (const float*)d_in[2];
    const float* vW1    = (const float*)d_in[3];
    const float* vb1    = (const float*)d_in[4];
    const float* vW2    = (const float*)d_in[5];
    const float* vb2    = (const float*)d_in[6];
    const float* hW1    = (const float*)d_in[7];
    const float* hb1    = (const float*)d_in[8];
    const float* hW2    = (const float*)d_in[9];
    const float* hb2    = (const float*)d_in[10];
    const float* projW  = (const float*)d_in[11];
    const float* projb  = (const float*)d_in[12];
    float* out = (float*)d_out;

    _Float16* vbuf = (_Float16*)d_ws;                                   // f16, 16 MB
    _Float16* hbuf = (_Float16*)((char*)d_ws + (size_t)B_ * CL_ * T_ * D_ * sizeof(_Float16));

    // 512 blocks = (b, cl, tch(8), dhalf(2)); 512 threads; 64 KB dynamic LDS
    k_stage1<<<B_ * CL_ * 8 * 2, 512, 65536, stream>>>(mem, dim_pe, vW1, vb1, vW2, vb2, vbuf);
    k_stage2<<<B_ * CL_ * 16 * 4, 256, 0, stream>>>(vbuf, mem, hW1, hb1, hW2, hb2, hbuf);
    k_proj<<<256, 256, 0, stream>>>(hbuf, projW, projb, out);
}

// Round 18
// 166.045 us; speedup vs baseline: 1.8586x; 1.8586x over previous
//
#include <hip/hip_runtime.h>
#include <hip/hip_bf16.h>

#define B_ 2
#define L_ 256
#define T_ 250
#define D_ 1024
#define NH_ 16
#define DH_ 64
#define CRv_ 16
#define HID_ 64
#define CL_ 16
#define OUT_ 1024
#define MEMROWS_ 64001L
#define TCH_ 25
#define NTCH_ 10

#define AS1 __attribute__((address_space(1)))
#define AS3 __attribute__((address_space(3)))

typedef __attribute__((ext_vector_type(2))) _Float16 h16x2;
typedef __attribute__((ext_vector_type(8))) _Float16 h16x8;
typedef __attribute__((ext_vector_type(4))) float f32x4;
typedef __attribute__((ext_vector_type(16))) float f32x16;

__device__ __forceinline__ h16x2 cvt_pk(float lo, float hi) {
    return __builtin_bit_cast(h16x2, __builtin_amdgcn_cvt_pkrtz(lo, hi));
}
__device__ __forceinline__ unsigned cvt_pku(float lo, float hi) {
    return __builtin_bit_cast(unsigned, __builtin_amdgcn_cvt_pkrtz(lo, hi));
}

struct H4 { h16x2 a, b, c, d; };
__device__ __forceinline__ h16x8 packH4(h16x2 a, h16x2 b, h16x2 c, h16x2 d) {
    H4 h{a, b, c, d};
    return __builtin_bit_cast(h16x8, h);
}
struct U4 { unsigned a, b, c, d; };
__device__ __forceinline__ h16x8 packU4(unsigned a, unsigned b, unsigned c, unsigned d) {
    U4 u{a, b, c, d};
    return __builtin_bit_cast(h16x8, u);
}

// ---- guaranteed-VOP3P packed f16 ops ----
__device__ __forceinline__ unsigned pk_fma(unsigned a, unsigned b, unsigned c) {
    unsigned d; asm("v_pk_fma_f16 %0, %1, %2, %3" : "=v"(d) : "v"(a), "v"(b), "v"(c)); return d;
}
__device__ __forceinline__ unsigned pk_mul(unsigned a, unsigned b) {
    unsigned d; asm("v_pk_mul_f16 %0, %1, %2" : "=v"(d) : "v"(a), "v"(b)); return d;
}
__device__ __forceinline__ unsigned pk_add(unsigned a, unsigned b) {
    unsigned d; asm("v_pk_add_f16 %0, %1, %2" : "=v"(d) : "v"(a), "v"(b)); return d;
}
__device__ __forceinline__ unsigned pk_max(unsigned a, unsigned b) {
    unsigned d; asm("v_pk_max_f16 %0, %1, %2" : "=v"(d) : "v"(a), "v"(b)); return d;
}
__device__ __forceinline__ unsigned pk_min(unsigned a, unsigned b) {
    unsigned d; asm("v_pk_min_f16 %0, %1, %2" : "=v"(d) : "v"(a), "v"(b)); return d;
}

struct GC { unsigned c0, c1, c2, c3, c4, clo, chi; };
__device__ __forceinline__ GC make_gc() {
    GC g;
    g.c0  = cvt_pku( 1.5957600f,   1.5957600f);
    g.c1  = cvt_pku(-1.0445624f,  -1.0445624f);
    g.c2  = cvt_pku( 0.5417632f,   0.5417632f);
    g.c3  = cvt_pku(-0.15817472f, -0.15817472f);
    g.c4  = cvt_pku( 0.018604288f, 0.018604288f);
    g.clo = cvt_pku(-1.75f, -1.75f);
    g.chi = cvt_pku( 1.75f,  1.75f);
    return g;
}

// Packed-f16 gelu * w2 accumulate, PRE-HALVED input aH = x/2. 10 VOP3P / 2 values.
__device__ __forceinline__ void gelu_w2_asm(unsigned aH, unsigned w, unsigned& pacc, const GC& gc) {
    unsigned t = pk_min(pk_max(aH, gc.clo), gc.chi);
    unsigned s = pk_mul(t, t);
    unsigned p = pk_fma(gc.c4, s, gc.c3);
    p = pk_fma(p, s, gc.c2);
    p = pk_fma(p, s, gc.c1);
    p = pk_fma(p, s, gc.c0);
    unsigned e = pk_mul(t, p);
    unsigned g = pk_fma(aH, e, aH);
    pacc = pk_fma(g, w, pacc);
}

#define WAITV(n) asm volatile("s_waitcnt vmcnt(" #n ")" ::: "memory")
#define MEMBAR() asm volatile("" ::: "memory")

// ---- Stage 1: 32x32x16 MFMA v-MLP. 4-wave blocks, 16x256 f32 LDS tile,
// TRIPLE-buffered, prefetch distance 2, exact counted vmcnt, 1 barrier/iter.
__global__ __launch_bounds__(256, 3) void k_stage1(
    const float* __restrict__ mem, const float* __restrict__ dim_pe,
    const float* __restrict__ W1, const float* __restrict__ b1,
    const float* __restrict__ W2, const float* __restrict__ b2,
    _Float16* __restrict__ vbuf)
{
    extern __shared__ float stage[];            // [3][16][256] = 48 KB

    const int blk = blockIdx.x;                 // (((b*16+cl)*NTCH + tch)*4 + dq
    const int dq  = blk & 3;
    int r = blk >> 2;
    const int tch = r % NTCH_;
    r /= NTCH_;
    const int cl  = r & 15;
    const int b   = r >> 4;
    const int lane = threadIdx.x & 63;
    const int wv   = threadIdx.x >> 6;          // 0..3
    const int nh   = dq * 4 + wv;
    const int h    = lane >> 5;                 // k-half (cr 8h..8h+7)
    const int l31  = lane & 31;

    const float* membase = mem + (long)b * MEMROWS_ * D_;
    _Float16* vrow = vbuf + (long)(b * CL_ + cl) * T_ * D_;
    const int t0 = tch * TCH_;

    const GC gc = make_gc();

    // A-fragments (W1^T, pre-halved): lane: f = fh*32 + l31, k = 8h + j
    h16x8 afrag[2];
#pragma unroll
    for (int fh = 0; fh < 2; ++fh) {
        h16x2 q[4];
#pragma unroll
        for (int jp = 0; jp < 4; ++jp) {
            float w0 = 0.5f * W1[(nh * CRv_ + 8 * h + 2 * jp + 0) * HID_ + fh * 32 + l31];
            float w1 = 0.5f * W1[(nh * CRv_ + 8 * h + 2 * jp + 1) * HID_ + fh * 32 + l31];
            q[jp] = cvt_pk(w0, w1);
        }
        afrag[fh] = packH4(q[0], q[1], q[2], q[3]);
    }

    // C-input: b1/2, rows per 32x32 C layout: f = fh*32 + (r&3)+8*(r>>2)+4h
    f32x16 ci[2];
#pragma unroll
    for (int fh = 0; fh < 2; ++fh)
#pragma unroll
        for (int rr = 0; rr < 16; ++rr)
            ci[fh][rr] = 0.5f * b1[nh * HID_ + fh * 32 + (rr & 3) + 8 * (rr >> 2) + 4 * h];

    // W2 pk pairs matching acc reg pairs (2m,2m+1)
    unsigned w2u[2][8];
#pragma unroll
    for (int fh = 0; fh < 2; ++fh)
#pragma unroll
        for (int m = 0; m < 8; ++m) {
            const int flo = ((2 * m) & 3) + 8 * (m >> 1) + 4 * h + fh * 32;
            w2u[fh][m] = cvt_pku(W2[nh * HID_ + flo], W2[nh * HID_ + flo + 1]);
        }

    // pe addend for B-frags (f16 pairs along k): d = nh*64 + dh*32 + l31
    unsigned peq[2][4];
#pragma unroll
    for (int dh = 0; dh < 2; ++dh) {
        const int d0 = nh * DH_ + dh * 32 + l31;
#pragma unroll
        for (int m = 0; m < 4; ++m)
            peq[dh][m] = cvt_pku(dim_pe[(8 * h + 2 * m + 0) * D_ + d0],
                                 dim_pe[(8 * h + 2 * m + 1) * D_ + d0]);
    }
    const float b2s = b2[nh];

    // Staging: wave wv owns rows 4wv..4wv+3; one 1KB sequential load per row.
    const float* gp0 = membase + ((size_t)(cl * CRv_ + 4 * wv + 0) * T_ + t0) * D_ + dq * 256 + lane * 4;
    const float* gp1 = membase + ((size_t)(cl * CRv_ + 4 * wv + 1) * T_ + t0) * D_ + dq * 256 + lane * 4;
    const float* gp2 = membase + ((size_t)(cl * CRv_ + 4 * wv + 2) * T_ + t0) * D_ + dq * 256 + lane * 4;
    const float* gp3 = membase + ((size_t)(cl * CRv_ + 4 * wv + 3) * T_ + t0) * D_ + dq * 256 + lane * 4;

#define ISSUE(bf) do { \
    float* lb = stage + (bf) * 4096; \
    __builtin_amdgcn_global_load_lds((const AS1 void*)gp0, (AS3 void*)(lb + (4 * wv + 0) * 256), 16, 0, 0); \
    __builtin_amdgcn_global_load_lds((const AS1 void*)gp1, (AS3 void*)(lb + (4 * wv + 1) * 256), 16, 0, 0); \
    __builtin_amdgcn_global_load_lds((const AS1 void*)gp2, (AS3 void*)(lb + (4 * wv + 2) * 256), 16, 0, 0); \
    __builtin_amdgcn_global_load_lds((const AS1 void*)gp3, (AS3 void*)(lb + (4 * wv + 3) * 256), 16, 0, 0); \
    gp0 += D_; gp1 += D_; gp2 += D_; gp3 += D_; } while (0)

    ISSUE(0);                                   // L(t0) -> buf0
    ISSUE(1);                                   // L(t1) -> buf1
    int bcur = 0, bnext = 2;                    // buffer of tile tt; buffer for tile tt+2

#pragma unroll 1
    for (int tt = 0; tt < TCH_; ++tt) {
        // exact counted waits for L(tt); ops younger than it (per-wave):
        // t0: L1 (4). t1: L2,S0 (5). steady: S(t-2),L(t+1),S(t-1) = 6. t24: S22,S23 = 2.
        if (tt == 0)            WAITV(4);
        else if (tt == 1)       WAITV(5);
        else if (tt < TCH_ - 1) WAITV(6);
        else                    WAITV(2);
        __builtin_amdgcn_s_barrier();           // all waves' L(tt) landed; buf(tt-1) free
        MEMBAR();
        if (tt + 2 < TCH_) ISSUE(bnext);        // L(tt+2) into buffer read at iter tt-1

        const float* bufp = stage + bcur * 4096;

        // B-fragments: lane: d_local = l31, k = 8h + j; x + pe in f16
        h16x8 bfr[2];
#pragma unroll
        for (int dh = 0; dh < 2; ++dh) {
            const int col = wv * 64 + dh * 32 + l31;
            float x0 = bufp[(8 * h + 0) * 256 + col];
            float x1 = bufp[(8 * h + 1) * 256 + col];
            float x2 = bufp[(8 * h + 2) * 256 + col];
            float x3 = bufp[(8 * h + 3) * 256 + col];
            float x4 = bufp[(8 * h + 4) * 256 + col];
            float x5 = bufp[(8 * h + 5) * 256 + col];
            float x6 = bufp[(8 * h + 6) * 256 + col];
            float x7 = bufp[(8 * h + 7) * 256 + col];
            unsigned u0 = pk_add(cvt_pku(x0, x1), peq[dh][0]);
            unsigned u1 = pk_add(cvt_pku(x2, x3), peq[dh][1]);
            unsigned u2 = pk_add(cvt_pku(x4, x5), peq[dh][2]);
            unsigned u3 = pk_add(cvt_pku(x6, x7), peq[dh][3]);
            bfr[dh] = packU4(u0, u1, u2, u3);
        }

        unsigned p00 = 0u, p01 = 0u, p10 = 0u, p11 = 0u;
        {
            f32x16 a00 = __builtin_amdgcn_mfma_f32_32x32x16_f16(afrag[0], bfr[0], ci[0], 0, 0, 0);
            f32x16 a01 = __builtin_amdgcn_mfma_f32_32x32x16_f16(afrag[0], bfr[1], ci[0], 0, 0, 0);
#pragma unroll
            for (int m = 0; m < 8; ++m) {
                unsigned am0 = cvt_pku(a00[2 * m], a00[2 * m + 1]);
                gelu_w2_asm(am0, w2u[0][m], p00, gc);
                unsigned am1 = cvt_pku(a01[2 * m], a01[2 * m + 1]);
                gelu_w2_asm(am1, w2u[0][m], p01, gc);
            }
        }
        {
            f32x16 a10 = __builtin_amdgcn_mfma_f32_32x32x16_f16(afrag[1], bfr[0], ci[1], 0, 0, 0);
            f32x16 a11 = __builtin_amdgcn_mfma_f32_32x32x16_f16(afrag[1], bfr[1], ci[1], 0, 0, 0);
#pragma unroll
            for (int m = 0; m < 8; ++m) {
                unsigned am0 = cvt_pku(a10[2 * m], a10[2 * m + 1]);
                gelu_w2_asm(am0, w2u[1][m], p10, gc);
                unsigned am1 = cvt_pku(a11[2 * m], a11[2 * m + 1]);
                gelu_w2_asm(am1, w2u[1][m], p11, gc);
            }
        }

        // Reduce: f-halves, cross-pk-half in f32, one shfl_xor(32)
        h16x2 pd0 = __builtin_bit_cast(h16x2, pk_add(p00, p10));
        h16x2 pd1 = __builtin_bit_cast(h16x2, pk_add(p01, p11));
        float o0 = (float)pd0[0] + (float)pd0[1];
        float o1 = (float)pd1[0] + (float)pd1[1];
        o0 += __shfl_xor(o0, 32);
        o1 += __shfl_xor(o1, 32);
        float ov = (h == 0) ? o0 : o1;
        vrow[(size_t)(t0 + tt) * D_ + nh * DH_ + lane] = (_Float16)(ov + b2s);
        MEMBAR();

        bcur  = (bcur == 2)  ? 0 : bcur + 1;
        bnext = (bnext == 2) ? 0 : bnext + 1;
    }
#undef ISSUE
}

// ---- Stage 2: h-MLP over t = tc*16+cr (pad rows -> nonsense); 16x16 path, f16 out.
__global__ __launch_bounds__(256) void k_stage2(
    const _Float16* __restrict__ vbuf, const float* __restrict__ mem,
    const float* __restrict__ W1, const float* __restrict__ b1,
    const float* __restrict__ W2, const float* __restrict__ b2,
    _Float16* __restrict__ hbuf)
{
    const int blk = blockIdx.x;                // ((b*CL + cl)*16 + tc)*4 + nhg
    const int nhg = blk & 3;
    const int tc  = (blk >> 2) & 15;
    const int cl  = (blk >> 6) & 15;
    const int b   = blk >> 10;
    const int lane = threadIdx.x & 63;
    const int wv   = threadIdx.x >> 6;
    const int nh   = nhg * 4 + wv;
    const int g    = lane >> 4;
    const int fl   = lane & 15;
    const int kbase = (8 * g) & 15;
    const bool klive = (g < 2);

    const _Float16* vrow = vbuf + (long)(b * CL_ + cl) * T_ * D_;
    const float* nons = mem + ((long)b * MEMROWS_ + (long)L_ * T_) * D_;

    const GC gc = make_gc();

    h16x8 bfragA[4];
    f32x4 ci[4];
    unsigned w2u[8];
#pragma unroll
    for (int cn = 0; cn < 4; ++cn) {
        h16x2 q[4];
#pragma unroll
        for (int jp = 0; jp < 4; ++jp) {
            float w0 = 0.5f * W1[(nh * CRv_ + kbase + 2 * jp + 0) * HID_ + cn * 16 + fl];
            float w1 = 0.5f * W1[(nh * CRv_ + kbase + 2 * jp + 1) * HID_ + cn * 16 + fl];
            h16x2 qq = cvt_pk(w0, w1);
            if (!klive) { qq[0] = (_Float16)0.f; qq[1] = (_Float16)0.f; }
            q[jp] = qq;
        }
        bfragA[cn] = packH4(q[0], q[1], q[2], q[3]);
#pragma unroll
        for (int r = 0; r < 4; ++r) ci[cn][r] = 0.5f * b1[nh * HID_ + cn * 16 + 4 * g + r];
        w2u[2 * cn + 0] = cvt_pku(W2[nh * HID_ + cn * 16 + 4 * g + 0],
                                  W2[nh * HID_ + cn * 16 + 4 * g + 1]);
        w2u[2 * cn + 1] = cvt_pku(W2[nh * HID_ + cn * 16 + 4 * g + 2],
                                  W2[nh * HID_ + cn * 16 + 4 * g + 3]);
    }
    const float b2s = b2[nh];

#pragma unroll 1
    for (int ct = 0; ct < 4; ++ct) {
        const int d0 = nh * DH_ + ct * 16 + fl;
        const _Float16 nv = (_Float16)nons[d0];

        h16x2 q[4];
#pragma unroll
        for (int jp = 0; jp < 4; ++jp) {
            h16x2 qq;
#pragma unroll
            for (int e = 0; e < 2; ++e) {
                const int t   = tc * CRv_ + kbase + 2 * jp + e;
                const int tcl = (t < T_) ? t : (T_ - 1);
                _Float16 us = vrow[tcl * D_ + d0];
                qq[e] = (t < T_) ? us : nv;
            }
            q[jp] = qq;
        }
        h16x8 af = packH4(q[0], q[1], q[2], q[3]);

        f32x4 acc[4];
#pragma unroll
        for (int cn = 0; cn < 4; ++cn)
            acc[cn] = __builtin_amdgcn_mfma_f32_16x16x32_f16(bfragA[cn], af, ci[cn], 0, 0, 0);

        unsigned pc0 = 0u, pc1 = 0u;
#pragma unroll
        for (int cn = 0; cn < 4; ++cn) {
            unsigned a01 = cvt_pku(acc[cn][0], acc[cn][1]);
            unsigned a23 = cvt_pku(acc[cn][2], acc[cn][3]);
            gelu_w2_asm(a01, w2u[2 * cn + 0], pc0, gc);
            gelu_w2_asm(a23, w2u[2 * cn + 1], pc1, gc);
        }
        h16x2 P = __builtin_bit_cast(h16x2, pk_add(pc0, pc1));
        float pr = (float)P[0] + (float)P[1];
        pr += __shfl_xor(pr, 16);
        pr += __shfl_xor(pr, 32);

        if (g == 0)
            hbuf[(long)((b * CL_ + cl) * 16 + tc) * D_ + d0] = (_Float16)(pr + b2s);
    }
}

// ---- Stage 3: C(512x1024) = H(f16) @ Wp^T + bias via f16 MFMA, f32 accum.
__global__ __launch_bounds__(256) void k_proj(
    const _Float16* __restrict__ H, const float* __restrict__ Wp,
    const float* __restrict__ bias, float* __restrict__ Cout)
{
    __shared__ _Float16 Ht[64][40];
    __shared__ _Float16 Wt[32][40];

    const int bn = blockIdx.x & 31;
    const int bm = blockIdx.x >> 5;
    const int tid = threadIdx.x;
    const int lane = tid & 63, wv = tid >> 6;
    const int g = lane >> 4, fl = lane & 15;
    const int m0 = bm * 64, n0 = bn * 32;

    const int hrow = tid >> 2, hko = (tid & 3) * 8;
    const int wrow = tid >> 3, wko = (tid & 7) * 4;

    const int nw  = (wv & 1) * 16;
    const int mwb = (wv >> 1) * 32;

    f32x4 acc[2] = {{0.f,0.f,0.f,0.f},{0.f,0.f,0.f,0.f}};

    for (int k0 = 0; k0 < 1024; k0 += 32) {
        uint4 hv = *reinterpret_cast<const uint4*>(&H[(size_t)(m0 + hrow) * OUT_ + k0 + hko]);
        *reinterpret_cast<uint4*>(&Ht[hrow][hko]) = hv;
        float4 wf = *reinterpret_cast<const float4*>(&Wp[(size_t)(n0 + wrow) * D_ + k0 + wko]);
        uint2 wu;
        wu.x = cvt_pku(wf.x, wf.y);
        wu.y = cvt_pku(wf.z, wf.w);
        *reinterpret_cast<uint2*>(&Wt[wrow][wko]) = wu;
        __syncthreads();

        h16x8 wfrag = *reinterpret_cast<const h16x8*>(&Wt[nw + fl][g * 8]);
        h16x8 hfrag0 = *reinterpret_cast<const h16x8*>(&Ht[mwb +  0 + fl][g * 8]);
        h16x8 hfrag1 = *reinterpret_cast<const h16x8*>(&Ht[mwb + 16 + fl][g * 8]);
        acc[0] = __builtin_amdgcn_mfma_f32_16x16x32_f16(hfrag0, wfrag, acc[0], 0, 0, 0);
        acc[1] = __builtin_amdgcn_mfma_f32_16x16x32_f16(hfrag1, wfrag, acc[1], 0, 0, 0);
        __syncthreads();
    }

    const int n = n0 + nw + fl;
    const float bv = bias[n];
#pragma unroll
    for (int mt = 0; mt < 2; ++mt) {
#pragma unroll
        for (int r = 0; r < 4; ++r) {
            const int m = m0 + mwb + mt * 16 + 4 * g + r;
            Cout[(size_t)m * OUT_ + n] = acc[mt][r] + bv;
        }
    }
}

extern "C" void kernel_launch(void* const* d_in, const int* in_sizes, int n_in,
                              void* d_out, int out_size, void* d_ws, size_t ws_size,
                              hipStream_t stream) {
    const float* mem    = (const float*)d_in[0];
    const float* dim_pe = (const float*)d_in[2];
    const float* vW1    = (const float*)d_in[3];
    const float* vb1    = (const float*)d_in[4];
    const float* vW2    = (const float*)d_in[5];
    const float* vb2    = (const float*)d_in[6];
    const float* hW1    = (const float*)d_in[7];
    const float* hb1    = (const float*)d_in[8];
    const float* hW2    = (const float*)d_in[9];
    const float* hb2    = (const float*)d_in[10];
    const float* projW  = (const float*)d_in[11];
    const float* projb  = (const float*)d_in[12];
    float* out = (float*)d_out;

    _Float16* vbuf = (_Float16*)d_ws;                                   // f16, 16 MB
    _Float16* hbuf = (_Float16*)((char*)d_ws + (size_t)B_ * CL_ * T_ * D_ * sizeof(_Float16));

    // 2560 blocks = (b, cl, tch(10), dq(4)); 256 threads; 48 KB dynamic LDS
    k_stage1<<<B_ * CL_ * NTCH_ * 4, 256, 49152, stream>>>(mem, dim_pe, vW1, vb1, vW2, vb2, vbuf);
    k_stage2<<<B_ * CL_ * 16 * 4, 256, 0, stream>>>(vbuf, mem, hW1, hb1, hW2, hb2, hbuf);
    k_proj<<<256, 256, 0, stream>>>(hbuf, projW, projb, out);
}